// Round 9
// baseline (693.247 us; speedup 1.0000x reference)
//
#include <hip/hip_runtime.h>
#include <hip/hip_bf16.h>

// Encoder: attention-weighted LSTM, B=32768 T=9 D_IN=81 H=128.
// All inputs AND outputs fp32. attn = softmax(pre) is time-invariant
// (logits = pre + scalar broadcast); Wh/Wc dead. Recurrence:
// gates_t = [w_in_t | h_t] @ [W_ih | W_hh]^T + bias.
//
// History:
//  r1: MFMA rewrite 403us (256th, acc[2][8], 192 regs, occ 22%).
//  r3/r4: occupancy chase regressed: r3 spilled (unified VGPR/AGPR budget),
//      r4 (kNB32/512th shape, occ 43%) drowned in NT partial-line store
//      amplification + NT no-allocate loads (2.73GB HBM).
//  r5: staged out_h quarter-line NT: WRITE 1.71GB. LESSON: NT only when
//      each lane-cluster covers full 64B lines; else plain (L2 merges).
//  r8: r1 shape + store fixes: 381us. WRITE 569MB, FETCH 748MB, but
//      MfmaUtil 14.5 / occ 21% / HBM 43% -- ALL pipes half-idle =>
//      latency-bound at 8 waves/CU (192 regs/wave).
//  r9 (this): r4's SHAPE + r8's STORES. kNB=32, kTh=512, 8 waves,
//      wave = 64 gate-rows x 32 batches (acc[2][4]=32 acc regs, ~96
//      total/wave -> ~16 waves/CU, 2 blocks/CU co-resident). Traffic
//      discipline unchanged from r8: plain cached x/W loads, plain
//      out_w stores, full-line NT out_h via LDS staging (hi+lo).
// MFMA layout (HW-verified C/D: col=lane&15=batch, row=(lane>>4)*4+reg=p):
// A = W^T tile (M=gate-row p), B = activations^T (N=batch); both operands
// contiguous-8-along-k so internal k-permutation cancels. Gate-row perm
// p=4u+q => lane's f32x4 acc = {i,f,g,o} of one (b,u): pointwise lane-local.
// fp32 activation accuracy via bf16 hi+lo planes (2 MFMAs per W fragment).

namespace {

constexpr int kB    = 32768;
constexpr int kT    = 9;
constexpr int kD    = 81;     // D_IN
constexpr int kH    = 128;
constexpr int kG    = 512;    // 4H
constexpr int kKPad = 224;    // 7 MFMA k-steps of 32; k<128: h, 128..208: w_in,
                              // 209..223: zero pad
constexpr int kNB   = 32;     // batch rows per block
constexpr int kTh   = 512;    // threads per block (8 waves)
constexpr int kAS   = 232;    // LDS activation row stride in bf16 (464B = 29*16:
                              // rows 16B-aligned; dword stride 116 == 20 mod 32
                              // -> 2-way bank alias, free)

// ws layout: [Wt bf16 [512][224] gate-permuted rows][bias 512 f32][Wx 16 f32][b_attn f32]
constexpr int kWsWtBytes  = kG * kKPad * 2;      // 229376
constexpr int kWsBiasOff  = kWsWtBytes;
constexpr int kWsWxOff    = kWsBiasOff + kG * 4;
constexpr int kWsBAttnOff = kWsWxOff + 16 * 4;

typedef __bf16 bf16x8 __attribute__((ext_vector_type(8)));
typedef __bf16 bf16x4 __attribute__((ext_vector_type(4)));
typedef float  f32x4  __attribute__((ext_vector_type(4)));

__device__ __forceinline__ float sigf(float x) {
  return __builtin_amdgcn_rcpf(1.f + __expf(-x));
}
// tanh(x) = 1 - 2/(1+e^{2x}); saturates correctly as exp -> 0/inf
__device__ __forceinline__ float tanhfast(float x) {
  return 1.f - 2.f * __builtin_amdgcn_rcpf(1.f + __expf(2.f * x));
}

// ---- prep: repack weights. Gate-row perm p = u*4+q (gate g = q*128+u).
// W stored TRANSPOSED [p][k] bf16, k-layout matching LDS activations:
// k<128 -> W_hh[g][k]; 128<=k<209 -> W_ih[g][k-128]; else 0.
__global__ void prep_kernel(const float* __restrict__ W_attn,
                            const float* __restrict__ b_attn,
                            const float* __restrict__ W_ih,
                            const float* __restrict__ W_hh,
                            const float* __restrict__ b_ih,
                            const float* __restrict__ b_hh,
                            unsigned char* __restrict__ ws) {
  __bf16* Wt   = reinterpret_cast<__bf16*>(ws);
  float* biasp = reinterpret_cast<float*>(ws + kWsBiasOff);
  float* wxp   = reinterpret_cast<float*>(ws + kWsWxOff);
  float* bap   = reinterpret_cast<float*>(ws + kWsBAttnOff);
  int tid = blockIdx.x * blockDim.x + threadIdx.x;
  int nth = gridDim.x * blockDim.x;
  for (int idx = tid; idx < kG * kKPad; idx += nth) {
    int p = idx / kKPad, k = idx - p * kKPad;
    int u = p >> 2, q = p & 3, g = q * kH + u;
    float v = 0.f;
    if (k < kH)           v = W_hh[g * kH + k];
    else if (k < kH + kD) v = W_ih[g * kD + (k - kH)];
    Wt[idx] = (__bf16)v;   // idx == p*kKPad + k
  }
  if (tid < kG) {
    int u = tid >> 2, q = tid & 3, g = q * kH + u;
    biasp[tid] = b_ih[g] + b_hh[g];
  }
  if (tid >= kG && tid < kG + 16) {
    int t = tid - kG;
    wxp[t] = (t < kT) ? W_attn[2 * kH + t] : 0.f;
  }
  if (tid == kG + 16) bap[0] = b_attn[0];
}

__global__ __launch_bounds__(kTh, 4) void enc_main(
    const float* __restrict__ x,              // (B,9,81) fp32
    const unsigned char* __restrict__ ws,
    float* __restrict__ out_w,                // (B,9,81) fp32
    float* __restrict__ out_h) {              // (B,9,128) fp32
  // Activations^T [b][k] bf16 hi/lo planes. k<128: h, 128..208: w_in, pad 0.
  __shared__ __align__(16) __bf16 ash[kNB][kAS];
  __shared__ __align__(16) __bf16 asl[kNB][kAS];
  __shared__ __align__(16) float bias_s[kG];
  __shared__ float red[kNB][16];
  __shared__ float wx_s[16];
  __shared__ float battn_s;

  const int tid = threadIdx.x;
  const int b0  = blockIdx.x * kNB;
  const __bf16* Wt = reinterpret_cast<const __bf16*>(ws);

  if (tid < 16) wx_s[tid] = reinterpret_cast<const float*>(ws + kWsWxOff)[tid];
  if (tid == 16) battn_s = reinterpret_cast<const float*>(ws + kWsBAttnOff)[0];
  bias_s[tid] = reinterpret_cast<const float*>(ws + kWsBiasOff)[tid];
  for (int i = tid; i < kNB * kAS; i += kTh) {   // zero (h0=0, k-pads=0)
    (&ash[0][0])[i] = (__bf16)0.f;
    (&asl[0][0])[i] = (__bf16)0.f;
  }
  __syncthreads();

  // ---- pre + softmax (time-invariant). 16 threads per batch row:
  //      b = tid>>4, d = (tid&15) + 16m, m<6. Captures x(t=0) into xr.
  const int sb = tid >> 4;
  const int sq = tid & 15;
  const size_t xbase = (size_t)(b0 + sb) * kT * kD;
  float attn[6];
  float xr[6];
  {
    float lmax = -3.4e38f;
#pragma unroll
    for (int m = 0; m < 6; ++m) {
      int d = sq + 16 * m;
      float s = -3.4e38f;
      xr[m] = 0.f;
      if (d < kD) {
        s = battn_s;
#pragma unroll
        for (int t = 0; t < kT; ++t) {
          float xv = x[xbase + t * kD + d];
          if (t == 0) xr[m] = xv;
          s += xv * wx_s[t];
        }
        lmax = fmaxf(lmax, s);
      }
      attn[m] = s;
    }
    red[sb][sq] = lmax;
    __syncthreads();
    float gmax = red[sb][0];
#pragma unroll
    for (int r = 1; r < 16; ++r) gmax = fmaxf(gmax, red[sb][r]);
    __syncthreads();
    float lsum = 0.f;
#pragma unroll
    for (int m = 0; m < 6; ++m) {
      float e = __expf(attn[m] - gmax);   // invalid lanes: exp(-huge) = 0
      attn[m] = e;
      lsum += e;
    }
    red[sb][sq] = lsum;
    __syncthreads();
    float tot = 0.f;
#pragma unroll
    for (int r = 0; r < 16; ++r) tot += red[sb][r];
    float inv = 1.0f / tot;
#pragma unroll
    for (int m = 0; m < 6; ++m) attn[m] *= inv;
  }

  // ---- prologue: w_in(0) = attn * x(0): store out_w (plain) + LDS hi/lo.
#pragma unroll
  for (int m = 0; m < 6; ++m) {
    int d = sq + 16 * m;
    if (d < kD) {
      float w = attn[m] * xr[m];
      out_w[xbase + d] = w;
      __bf16 hi = (__bf16)w;
      ash[sb][kH + d] = hi;
      asl[sb][kH + d] = (__bf16)(w - (float)hi);
    }
  }

  // MFMA ids: wave wv owns gate-rows [wv*64,(wv+1)*64) (4 p-tiles), 32 b.
  const int lane = tid & 63;
  const int wv   = tid >> 6;
  const int lb   = lane & 15;
  const int kg   = lane >> 4;
  const __bf16* wrow = Wt + (size_t)(wv * 64 + lb) * kKPad;

  float c_reg[2][4];
#pragma unroll
  for (int bt = 0; bt < 2; ++bt)
#pragma unroll
    for (int p = 0; p < 4; ++p) c_reg[bt][p] = 0.f;

  __syncthreads();   // w_in(0) visible to all waves

  for (int t = 0; t < kT; ++t) {
    // ---- issue x(t+1) loads early: vmem latency overlaps the MFMA block
    if (t + 1 < kT) {
      const size_t xoff1 = xbase + (size_t)(t + 1) * kD;
#pragma unroll
      for (int m = 0; m < 6; ++m) {
        int d = sq + 16 * m;
        if (d < kD) xr[m] = x[xoff1 + d];
      }
    }

    // ---- gates = act @ W^T via MFMA, acc init = bias quad
    f32x4 acc[2][4];
#pragma unroll
    for (int p = 0; p < 4; ++p) {
      f32x4 bv = *reinterpret_cast<const f32x4*>(
          &bias_s[wv * 64 + p * 16 + kg * 4]);
      acc[0][p] = bv;
      acc[1][p] = bv;
    }
#pragma unroll
    for (int ks = 0; ks < kKPad / 32; ++ks) {
      const int k0 = ks * 32 + kg * 8;
      bf16x8 wf[4];
#pragma unroll
      for (int p = 0; p < 4; ++p)
        wf[p] = *reinterpret_cast<const bf16x8*>(wrow + p * (16 * kKPad) + k0);
#pragma unroll
      for (int bt = 0; bt < 2; ++bt) {
        bf16x8 bh = *reinterpret_cast<const bf16x8*>(&ash[bt * 16 + lb][k0]);
        bf16x8 bl = *reinterpret_cast<const bf16x8*>(&asl[bt * 16 + lb][k0]);
#pragma unroll
        for (int p = 0; p < 4; ++p) {
          acc[bt][p] = __builtin_amdgcn_mfma_f32_16x16x32_bf16(wf[p], bh, acc[bt][p], 0, 0, 0);
          acc[bt][p] = __builtin_amdgcn_mfma_f32_16x16x32_bf16(wf[p], bl, acc[bt][p], 0, 0, 0);
        }
      }
    }

    // ---- w_in(t+1) = attn * x(t+1): out_w store (PLAIN: L2 merges the
    // 64B clusters). Keep w in xr for the LDS staging after barB.
    if (t + 1 < kT) {
      const size_t xoff1 = xbase + (size_t)(t + 1) * kD;
#pragma unroll
      for (int m = 0; m < 6; ++m) {
        int d = sq + 16 * m;
        if (d < kD) {
          float w = attn[m] * xr[m];
          out_w[xoff1 + d] = w;
          xr[m] = w;
        }
      }
    }
    __syncthreads();   // barB: all GEMM LDS reads done before rewrites

    // ---- LSTM pointwise: lane holds {i,f,g,o} of (b = bt*16+lb, u).
    //      u = wv*16 + p*4 + kg (gate-row = wv*64 + p*16 + kg*4 + reg).
#pragma unroll
    for (int p = 0; p < 4; ++p) {
      const int u = wv * 16 + p * 4 + kg;
#pragma unroll
      for (int bt = 0; bt < 2; ++bt) {
        f32x4 g4 = acc[bt][p];
        float cn = sigf(g4[1]) * c_reg[bt][p] + sigf(g4[0]) * tanhfast(g4[2]);
        float hn = sigf(g4[3]) * tanhfast(cn);
        c_reg[bt][p] = cn;
        const int b = bt * 16 + lb;
        __bf16 hi = (__bf16)hn;
        ash[b][u] = hi;                             // h region, k = u
        asl[b][u] = (__bf16)(hn - (float)hi);
      }
    }
    // ---- stage w_in(t+1) into LDS (region already read by GEMM(t))
    if (t + 1 < kT) {
#pragma unroll
      for (int m = 0; m < 6; ++m) {
        int d = sq + 16 * m;
        if (d < kD) {
          float w = xr[m];
          __bf16 hi = (__bf16)w;
          ash[sb][kH + d] = hi;
          asl[sb][kH + d] = (__bf16)(w - (float)hi);
        }
      }
    }
    __syncthreads();   // barC: h(t) + w_in(t+1) visible

    // ---- out_h(t) store, FULL-LINE NT: thread (row sb=tid>>4, seg sq);
    // store j at float offset sq*4 + j*64 => per instruction each 16-lane
    // row-cluster covers 256B contiguous (4 full 64B lines; row base
    // (b*9+t)*512B is line-aligned). h = hi+lo (err ~4e-6 << 4.9e-4).
    {
      float* orow = out_h + ((size_t)(b0 + sb) * kT + t) * kH;
#pragma unroll
      for (int j = 0; j < 2; ++j) {
        const int o = sq * 4 + j * 64;
        bf16x4 h4 = *reinterpret_cast<const bf16x4*>(&ash[sb][o]);
        bf16x4 l4 = *reinterpret_cast<const bf16x4*>(&asl[sb][o]);
        f32x4 v;
#pragma unroll
        for (int i = 0; i < 4; ++i) v[i] = (float)h4[i] + (float)l4[i];
        __builtin_nontemporal_store(v, reinterpret_cast<f32x4*>(orow + o));
      }
    }
    // no barrier: this store phase and the next GEMM both only READ LDS;
    // next writes (h, w_in) are after next barB.
  }
}

}  // namespace

extern "C" void kernel_launch(void* const* d_in, const int* in_sizes, int n_in,
                              void* d_out, int out_size, void* d_ws, size_t ws_size,
                              hipStream_t stream) {
  (void)in_sizes; (void)n_in; (void)out_size; (void)ws_size;
  const float* x      = (const float*)d_in[0];
  const float* W_attn = (const float*)d_in[1];
  const float* b_attn = (const float*)d_in[2];
  const float* W_ih   = (const float*)d_in[3];
  const float* W_hh   = (const float*)d_in[4];
  const float* b_ih   = (const float*)d_in[5];
  const float* b_hh   = (const float*)d_in[6];
  float* out_w = (float*)d_out;
  float* out_h = out_w + (size_t)kB * kT * kD;
  unsigned char* ws = (unsigned char*)d_ws;

  hipLaunchKernelGGL(prep_kernel, dim3(64), dim3(256), 0, stream,
                     W_attn, b_attn, W_ih, W_hh, b_ih, b_hh, ws);
  hipLaunchKernelGGL(enc_main, dim3(kB / kNB), dim3(kTh), 0, stream,
                     x, ws, out_w, out_h);
}

// Round 10
// 632.569 us; speedup vs baseline: 1.0959x; 1.0959x over previous
//
#include <hip/hip_runtime.h>
#include <hip/hip_bf16.h>

// Encoder: attention-weighted LSTM, B=32768 T=9 D_IN=81 H=128.
// All inputs AND outputs fp32. attn = softmax(pre) is time-invariant
// (logits = pre + scalar broadcast); Wh/Wc dead. Recurrence:
// gates_t = [w_in_t | h_t] @ [W_ih | W_hh]^T + bias.
//
// History:
//  r1: MFMA rewrite 403us (256th, acc[2][8], all-PLAIN stores: WRITE 373MB).
//  r3/r4: occupancy chase regressed: spills (unified VGPR/AGPR budget) and
//      NT partial-line store amplification (2.7GB HBM).
//  r5: staged out_h quarter-line NT: WRITE 1.71GB.
//  r8: r1 shape + staged full-line NT out_h + plain out_w: 381us.
//      WRITE 569MB (ideal 247!) -- NT f32x4 stores amplify ~2x even with
//      full-line lane clusters, and add RMW fetches.
//  r9: r4 shape (512th, occ 43%): 451us. Traffic GREW (+350MB); dur tracks
//      bytes/achieved-BW in both r8/r9 => kernel is traffic-bound, not
//      occupancy-bound. LESSON: on gfx950 prefer PLAIN stores through L2
//      (write-allocate merges, full-line writeback); avoid NT stores
//      entirely for these access shapes.
//  r10 (this): r8 verbatim, out_h store PLAIN (drop NT; keep LDS-staged
//      mapping: each instruction's 8-lane cluster = 2 full 64B lines,
//      128B-aligned => L2 full-line write, no RMW fill). All stores plain.
// MFMA layout (HW-verified C/D: col=lane&15=batch, row=(lane>>4)*4+reg=p):
// A = W^T tile (M=gate-row p), B = activations^T (N=batch); both operands
// contiguous-8-along-k so internal k-permutation cancels. Gate-row perm
// p=4u+q => lane's f32x4 acc = {i,f,g,o} of one (b,u): pointwise lane-local.
// fp32 activation accuracy via bf16 hi+lo planes (2 MFMAs per W fragment).

namespace {

constexpr int kB    = 32768;
constexpr int kT    = 9;
constexpr int kD    = 81;     // D_IN
constexpr int kH    = 128;
constexpr int kG    = 512;    // 4H
constexpr int kKPad = 224;    // 7 MFMA k-steps of 32; k<128: h, 128..208: w_in,
                              // 209..223: zero pad
constexpr int kNB   = 32;     // batch rows per block
constexpr int kTh   = 256;    // threads per block (4 waves)
constexpr int kAS   = 232;    // LDS activation row stride in bf16 (464B = 29*16:
                              // rows 16B-aligned; dword stride 116 == 20 mod 32
                              // -> 2-way bank alias, free)

// ws layout: [Wt bf16 [512][224] gate-permuted rows][bias 512 f32][Wx 16 f32][b_attn f32]
constexpr int kWsWtBytes  = kG * kKPad * 2;      // 229376
constexpr int kWsBiasOff  = kWsWtBytes;
constexpr int kWsWxOff    = kWsBiasOff + kG * 4;
constexpr int kWsBAttnOff = kWsWxOff + 16 * 4;

typedef __bf16 bf16x8 __attribute__((ext_vector_type(8)));
typedef __bf16 bf16x4 __attribute__((ext_vector_type(4)));
typedef float  f32x4  __attribute__((ext_vector_type(4)));

__device__ __forceinline__ float sigf(float x) {
  return __builtin_amdgcn_rcpf(1.f + __expf(-x));
}
// tanh(x) = 1 - 2/(1+e^{2x}); saturates correctly as exp -> 0/inf
__device__ __forceinline__ float tanhfast(float x) {
  return 1.f - 2.f * __builtin_amdgcn_rcpf(1.f + __expf(2.f * x));
}

// ---- prep: repack weights. Gate-row perm p = u*4+q (gate g = q*128+u).
// W stored TRANSPOSED [p][k] bf16, k-layout matching LDS activations:
// k<128 -> W_hh[g][k]; 128<=k<209 -> W_ih[g][k-128]; else 0.
__global__ void prep_kernel(const float* __restrict__ W_attn,
                            const float* __restrict__ b_attn,
                            const float* __restrict__ W_ih,
                            const float* __restrict__ W_hh,
                            const float* __restrict__ b_ih,
                            const float* __restrict__ b_hh,
                            unsigned char* __restrict__ ws) {
  __bf16* Wt   = reinterpret_cast<__bf16*>(ws);
  float* biasp = reinterpret_cast<float*>(ws + kWsBiasOff);
  float* wxp   = reinterpret_cast<float*>(ws + kWsWxOff);
  float* bap   = reinterpret_cast<float*>(ws + kWsBAttnOff);
  int tid = blockIdx.x * blockDim.x + threadIdx.x;
  int nth = gridDim.x * blockDim.x;
  for (int idx = tid; idx < kG * kKPad; idx += nth) {
    int p = idx / kKPad, k = idx - p * kKPad;
    int u = p >> 2, q = p & 3, g = q * kH + u;
    float v = 0.f;
    if (k < kH)           v = W_hh[g * kH + k];
    else if (k < kH + kD) v = W_ih[g * kD + (k - kH)];
    Wt[idx] = (__bf16)v;   // idx == p*kKPad + k
  }
  if (tid < kG) {
    int u = tid >> 2, q = tid & 3, g = q * kH + u;
    biasp[tid] = b_ih[g] + b_hh[g];
  }
  if (tid >= kG && tid < kG + 16) {
    int t = tid - kG;
    wxp[t] = (t < kT) ? W_attn[2 * kH + t] : 0.f;
  }
  if (tid == kG + 16) bap[0] = b_attn[0];
}

__global__ __launch_bounds__(kTh, 2) void enc_main(
    const float* __restrict__ x,              // (B,9,81) fp32
    const unsigned char* __restrict__ ws,
    float* __restrict__ out_w,                // (B,9,81) fp32
    float* __restrict__ out_h) {              // (B,9,128) fp32
  // Activations^T [b][k] bf16 hi/lo planes. k<128: h, 128..208: w_in, pad 0.
  __shared__ __align__(16) __bf16 ash[kNB][kAS];
  __shared__ __align__(16) __bf16 asl[kNB][kAS];
  __shared__ __align__(16) float bias_s[kG];
  __shared__ float red[kNB][8];
  __shared__ float wx_s[16];
  __shared__ float battn_s;

  const int tid = threadIdx.x;
  const int b0  = blockIdx.x * kNB;
  const __bf16* Wt = reinterpret_cast<const __bf16*>(ws);

  if (tid < 16) wx_s[tid] = reinterpret_cast<const float*>(ws + kWsWxOff)[tid];
  if (tid == 16) battn_s = reinterpret_cast<const float*>(ws + kWsBAttnOff)[0];
  bias_s[tid]       = reinterpret_cast<const float*>(ws + kWsBiasOff)[tid];
  bias_s[tid + 256] = reinterpret_cast<const float*>(ws + kWsBiasOff)[tid + 256];
  for (int i = tid; i < kNB * kAS; i += kTh) {   // zero (h0=0, k-pads=0)
    (&ash[0][0])[i] = (__bf16)0.f;
    (&asl[0][0])[i] = (__bf16)0.f;
  }
  __syncthreads();

  // ---- pre + softmax (time-invariant). thread: b = tid>>3, d = (tid&7)+8m.
  // Captures x(t=0) into xr during the pass.
  const int sb = tid >> 3;
  const int sq = tid & 7;
  const size_t xbase = (size_t)(b0 + sb) * kT * kD;
  float attn[11];
  float xr[11];
  {
    float lmax = -3.4e38f;
#pragma unroll
    for (int m = 0; m < 11; ++m) {
      int d = sq + 8 * m;
      float s = -3.4e38f;
      xr[m] = 0.f;
      if (d < kD) {
        s = battn_s;
#pragma unroll
        for (int t = 0; t < kT; ++t) {
          float xv = x[xbase + t * kD + d];
          if (t == 0) xr[m] = xv;
          s += xv * wx_s[t];
        }
        lmax = fmaxf(lmax, s);
      }
      attn[m] = s;
    }
    red[sb][sq] = lmax;
    __syncthreads();
    float gmax = red[sb][0];
#pragma unroll
    for (int r = 1; r < 8; ++r) gmax = fmaxf(gmax, red[sb][r]);
    __syncthreads();
    float lsum = 0.f;
#pragma unroll
    for (int m = 0; m < 11; ++m) {
      float e = __expf(attn[m] - gmax);   // invalid lanes: exp(-huge) = 0
      attn[m] = e;
      lsum += e;
    }
    red[sb][sq] = lsum;
    __syncthreads();
    float tot = 0.f;
#pragma unroll
    for (int r = 0; r < 8; ++r) tot += red[sb][r];
    float inv = 1.0f / tot;
#pragma unroll
    for (int m = 0; m < 11; ++m) attn[m] *= inv;
  }

  // ---- prologue: w_in(0) = attn * x(0): store out_w (plain) + LDS hi/lo.
#pragma unroll
  for (int m = 0; m < 11; ++m) {
    int d = sq + 8 * m;
    if (d < kD) {
      float w = attn[m] * xr[m];
      out_w[xbase + d] = w;
      __bf16 hi = (__bf16)w;
      ash[sb][kH + d] = hi;
      asl[sb][kH + d] = (__bf16)(w - (float)hi);
    }
  }

  // MFMA ids: wave wv owns gate-rows [wv*128,(wv+1)*128), 32 batches.
  const int lane = tid & 63;
  const int wv   = tid >> 6;
  const int lb   = lane & 15;
  const int kg   = lane >> 4;
  const __bf16* wrow = Wt + (size_t)(wv * 128 + lb) * kKPad;

  float c_reg[2][8];
#pragma unroll
  for (int bt = 0; bt < 2; ++bt)
#pragma unroll
    for (int p = 0; p < 8; ++p) c_reg[bt][p] = 0.f;

  __syncthreads();   // w_in(0) visible to all waves

  for (int t = 0; t < kT; ++t) {
    // ---- issue x(t+1) loads early: vmem latency overlaps the MFMA block
    if (t + 1 < kT) {
      const size_t xoff1 = xbase + (size_t)(t + 1) * kD;
#pragma unroll
      for (int m = 0; m < 11; ++m) {
        int d = sq + 8 * m;
        if (d < kD) xr[m] = x[xoff1 + d];
      }
    }

    // ---- gates = act @ W^T via MFMA, acc init = bias quad
    f32x4 acc[2][8];
#pragma unroll
    for (int p = 0; p < 8; ++p) {
      f32x4 bv = *reinterpret_cast<const f32x4*>(
          &bias_s[wv * 128 + p * 16 + kg * 4]);
      acc[0][p] = bv;
      acc[1][p] = bv;
    }
#pragma unroll
    for (int ks = 0; ks < kKPad / 32; ++ks) {
      const int k0 = ks * 32 + kg * 8;
      bf16x8 wf[8];
#pragma unroll
      for (int p = 0; p < 8; ++p)
        wf[p] = *reinterpret_cast<const bf16x8*>(wrow + p * (16 * kKPad) + k0);
#pragma unroll
      for (int bt = 0; bt < 2; ++bt) {
        bf16x8 bh = *reinterpret_cast<const bf16x8*>(&ash[bt * 16 + lb][k0]);
        bf16x8 bl = *reinterpret_cast<const bf16x8*>(&asl[bt * 16 + lb][k0]);
#pragma unroll
        for (int p = 0; p < 8; ++p) {
          acc[bt][p] = __builtin_amdgcn_mfma_f32_16x16x32_bf16(wf[p], bh, acc[bt][p], 0, 0, 0);
          acc[bt][p] = __builtin_amdgcn_mfma_f32_16x16x32_bf16(wf[p], bl, acc[bt][p], 0, 0, 0);
        }
      }
    }

    // ---- w_in(t+1) = attn * x(t+1): out_w store (PLAIN: L2 merges the
    // 32B clusters). Keep w in xr for the LDS staging after barB.
    if (t + 1 < kT) {
      const size_t xoff1 = xbase + (size_t)(t + 1) * kD;
#pragma unroll
      for (int m = 0; m < 11; ++m) {
        int d = sq + 8 * m;
        if (d < kD) {
          float w = attn[m] * xr[m];
          out_w[xoff1 + d] = w;
          xr[m] = w;
        }
      }
    }
    __syncthreads();   // barB: all GEMM LDS reads done before rewrites

    // ---- LSTM pointwise: lane holds {i,f,g,o} of (b = bt*16+lb, u).
#pragma unroll
    for (int p = 0; p < 8; ++p) {
      const int u = wv * 32 + p * 4 + kg;
#pragma unroll
      for (int bt = 0; bt < 2; ++bt) {
        f32x4 g4 = acc[bt][p];
        float cn = sigf(g4[1]) * c_reg[bt][p] + sigf(g4[0]) * tanhfast(g4[2]);
        float hn = sigf(g4[3]) * tanhfast(cn);
        c_reg[bt][p] = cn;
        const int b = bt * 16 + lb;
        __bf16 hi = (__bf16)hn;
        ash[b][u] = hi;                             // h region, k = u
        asl[b][u] = (__bf16)(hn - (float)hi);
      }
    }
    // ---- stage w_in(t+1) into LDS (region already read by GEMM(t))
    if (t + 1 < kT) {
#pragma unroll
      for (int m = 0; m < 11; ++m) {
        int d = sq + 8 * m;
        if (d < kD) {
          float w = xr[m];
          __bf16 hi = (__bf16)w;
          ash[sb][kH + d] = hi;
          asl[sb][kH + d] = (__bf16)(w - (float)hi);
        }
      }
    }
    __syncthreads();   // barC: h(t) + w_in(t+1) visible

    // ---- out_h(t) store, PLAIN full-line: thread (row sb, seg sq); store j
    // at float offset sq*4 + j*32 => per instruction the 8 lanes of each
    // sb-cluster cover 128B contiguous (2 full 64B lines, 128B-aligned:
    // row base (b*9+t)*512B). Plain stores: L2 full-line write, no NT
    // amplification (r8/r9 NT cost ~2-3x WRITE). h = hi+lo (err ~4e-6).
    {
      float* orow = out_h + ((size_t)(b0 + sb) * kT + t) * kH;
#pragma unroll
      for (int j = 0; j < 4; ++j) {
        const int o = sq * 4 + j * 32;
        bf16x4 h4 = *reinterpret_cast<const bf16x4*>(&ash[sb][o]);
        bf16x4 l4 = *reinterpret_cast<const bf16x4*>(&asl[sb][o]);
        f32x4 v;
#pragma unroll
        for (int i = 0; i < 4; ++i) v[i] = (float)h4[i] + (float)l4[i];
        *reinterpret_cast<f32x4*>(orow + o) = v;
      }
    }
    // no barrier: this store phase and the next GEMM both only READ LDS;
    // next writes (h, w_in) are after next barB.
  }
}

}  // namespace

extern "C" void kernel_launch(void* const* d_in, const int* in_sizes, int n_in,
                              void* d_out, int out_size, void* d_ws, size_t ws_size,
                              hipStream_t stream) {
  (void)in_sizes; (void)n_in; (void)out_size; (void)ws_size;
  const float* x      = (const float*)d_in[0];
  const float* W_attn = (const float*)d_in[1];
  const float* b_attn = (const float*)d_in[2];
  const float* W_ih   = (const float*)d_in[3];
  const float* W_hh   = (const float*)d_in[4];
  const float* b_ih   = (const float*)d_in[5];
  const float* b_hh   = (const float*)d_in[6];
  float* out_w = (float*)d_out;
  float* out_h = out_w + (size_t)kB * kT * kD;
  unsigned char* ws = (unsigned char*)d_ws;

  hipLaunchKernelGGL(prep_kernel, dim3(64), dim3(256), 0, stream,
                     W_attn, b_attn, W_ih, W_hh, b_ih, b_hh, ws);
  hipLaunchKernelGGL(enc_main, dim3(kB / kNB), dim3(kTh), 0, stream,
                     x, ws, out_w, out_h);
}